// Round 10
// baseline (553.455 us; speedup 1.0000x reference)
//
#include <hip/hip_runtime.h>
#include <math.h>

#define NTOK 2304      // 48*48 tokens
#define BATCH 2
#define CIN 256
#define HID 512        // 8 heads * 64
#define NH 8
#define LOG2E 1.44269504088896340736f
#define NBLK 288       // grid size; launch_bounds(256,2) -> capacity 512 >= 288

typedef __attribute__((ext_vector_type(8))) short bfrag;    // 8 bf16 (4 VGPRs)
typedef __attribute__((ext_vector_type(16))) float f32x16;  // MFMA 32x32 accumulator

#if __has_builtin(__builtin_amdgcn_exp2f)
#define EXP2(x) __builtin_amdgcn_exp2f(x)
#else
#define EXP2(x) exp2f(x)
#endif

// fp32 -> bf16 (RNE)
__device__ __forceinline__ unsigned f2bf(float f) {
    unsigned u = __float_as_uint(f);
    u += 0x7FFF + ((u >> 16) & 1);
    return u >> 16;
}

// pack trunc(hi(b)) , trunc(hi(a)) -> one dword {bf16(b):bf16(a)} in 1 v_perm
__device__ __forceinline__ unsigned pk_trunc(float a, float b) {
    return __builtin_amdgcn_perm(__float_as_uint(b), __float_as_uint(a), 0x07060302u);
}

// Software grid barrier (sense-reversal). bar[0]=arrive count, bar[1]=generation.
// AGENT-scope acquire/release atomics emit the L2 writeback/invalidate needed
// for cross-XCD visibility on gfx950. All NBLK blocks are resident by
// construction (launch_bounds(256,2): 2 blocks/CU * 256 CU = 512 >= 288).
__device__ __forceinline__ void gbar(unsigned* bar) {
    __syncthreads();
    if (threadIdx.x == 0) {
        unsigned gen = __hip_atomic_load(&bar[1], __ATOMIC_RELAXED,
                                         __HIP_MEMORY_SCOPE_AGENT);
        unsigned old = __hip_atomic_fetch_add(&bar[0], 1u, __ATOMIC_ACQ_REL,
                                              __HIP_MEMORY_SCOPE_AGENT);
        if (old == NBLK - 1) {
            __hip_atomic_store(&bar[0], 0u, __ATOMIC_RELAXED,
                               __HIP_MEMORY_SCOPE_AGENT);
            __hip_atomic_store(&bar[1], gen + 1u, __ATOMIC_RELEASE,
                               __HIP_MEMORY_SCOPE_AGENT);
        } else {
            while (__hip_atomic_load(&bar[1], __ATOMIC_ACQUIRE,
                                     __HIP_MEMORY_SCOPE_AGENT) == gen)
                __builtin_amdgcn_s_sleep(2);
        }
    }
    __syncthreads();
}

// exp2 + bf16-pack + lane^32 half-swap: accS (S^T quadrant, C-layout) ->
// two A-operand P frags; accumulates this lane's partial row sums.
__device__ __forceinline__ void softmax_frag(
    const f32x16& accS, int h, float& ps0, float& ps1, bfrag& P0, bfrag& P1)
{
    unsigned dw[8];
#pragma unroll
    for (int i = 0; i < 8; i++) {
        float plo = EXP2(accS[2 * i]);
        float phi = EXP2(accS[2 * i + 1]);
        dw[i] = pk_trunc(plo, phi);
        ps0 += __uint_as_float(dw[i] << 16);
        ps1 += __uint_as_float(dw[i] & 0xffff0000u);
    }
    unsigned sa0 = h ? dw[0] : dw[2], sb0 = h ? dw[1] : dw[3];
    unsigned sa1 = h ? dw[4] : dw[6], sb1 = h ? dw[5] : dw[7];
    unsigned ra0 = (unsigned)__shfl_xor((int)sa0, 32, 64);
    unsigned rb0 = (unsigned)__shfl_xor((int)sb0, 32, 64);
    unsigned ra1 = (unsigned)__shfl_xor((int)sa1, 32, 64);
    unsigned rb1 = (unsigned)__shfl_xor((int)sb1, 32, 64);
    union { bfrag f; unsigned u[4]; } U0, U1;
    U0.u[0] = h ? ra0 : dw[0];  U0.u[1] = h ? rb0 : dw[1];
    U0.u[2] = h ? dw[2] : ra0;  U0.u[3] = h ? dw[3] : rb0;
    U1.u[0] = h ? ra1 : dw[4];  U1.u[1] = h ? rb1 : dw[5];
    U1.u[2] = h ? dw[6] : ra1;  U1.u[3] = h ? dw[7] : rb1;
    P0 = U0.f; P1 = U1.f;
}

// ---------------------------------------------------------------------------
// Megakernel: whole pipeline, one dispatch, software grid barriers.
// Workspace map (<= 36,446,224 B):
//   [0, 18,874,368)           qkf fp32 [2][1024][2304]   (P1 -> P3)
//       then Opart fp32 [2 split][2][2304][512]          (P4 -> P5, exact fit)
//   [18,874,368, 23,592,960)  vb bf16 [2][512][2304]     (P1 -> P4)
//   [23,592,960, 33,030,144)  qkt bf16 [2][16][2304][64] (P3 -> P4)
//       then aoT bf16 [2][2304][512]                     (P5 -> P6)
//   [33,030,144, 33,325,056)  lsum fp32 [2][16][2304]    (P4 -> P5, over dead xT)
//   [33,030,144, 35,389,440)  xT bf16                     (P0 -> P1)
//   [35,389,440, 36,175,872)  wqb bf16
//   [36,175,872, 36,438,016)  wpb bf16
//   [36,438,016, 36,446,208)  invn fp32 [2048]
//   [36,446,208, 36,446,224)  barrier state (memset 0 on-stream pre-launch)
// ---------------------------------------------------------------------------
__global__ __launch_bounds__(256, 2) void mega(
    const float* __restrict__ x, const float* __restrict__ wq,
    const float* __restrict__ wp, const float* __restrict__ bias,
    float* __restrict__ y, char* __restrict__ wsb)
{
    float* qkf   = (float*)wsb;
    float* Opart = (float*)wsb;
    short* vbp   = (short*)(wsb + 18874368);
    short* qkt   = (short*)(wsb + 23592960);
    short* aoT   = (short*)(wsb + 23592960);
    float* lsum  = (float*)(wsb + 33030144);
    short* xT    = (short*)(wsb + 33030144);
    short* wqb   = (short*)(wsb + 35389440);
    short* wpb   = (short*)(wsb + 36175872);
    float* invn  = (float*)(wsb + 36438016);
    unsigned* bar = (unsigned*)(wsb + 36446208);

    __shared__ float sT[64][65];
    __shared__ float wsred[4];

    int bid = blockIdx.x, tid = threadIdx.x;
    int lane = tid & 63, wv = tid >> 6;
    int h = lane >> 5, l31 = lane & 31;

    // ================= P0: pack weights (256 units) + xT transpose (288) ===
    for (int u = bid; u < 544; u += NBLK) {
        if (u < 256) {
            int e = (u * 256 + tid) * 8;
            const int NQ = 1536 * 256;
            const float* src; short* dst;
            if (e < NQ) { src = wq + e; dst = wqb + e; }
            else        { src = wp + (e - NQ); dst = wpb + (e - NQ); }
            float4 v0 = ((const float4*)src)[0];
            float4 v1 = ((const float4*)src)[1];
            unsigned b0 = f2bf(v0.x) | (f2bf(v0.y) << 16);
            unsigned b1 = f2bf(v0.z) | (f2bf(v0.w) << 16);
            unsigned b2 = f2bf(v1.x) | (f2bf(v1.y) << 16);
            unsigned b3 = f2bf(v1.z) | (f2bf(v1.w) << 16);
            *((uint4*)dst) = make_uint4(b0, b1, b2, b3);
        } else {
            int idx = u - 256;
            int n0 = (idx % 36) * 64, c0 = ((idx / 36) & 3) * 64, b = idx / 144;
            for (int c = wv; c < 64; c += 4)
                sT[c][lane] = x[((size_t)b * CIN + c0 + c) * NTOK + n0 + lane];
            __syncthreads();
            int n = tid >> 2, c4 = (tid & 3) * 16;
            unsigned buf[8];
#pragma unroll
            for (int i = 0; i < 8; i++)
                buf[i] = f2bf(sT[c4 + 2 * i][n]) | (f2bf(sT[c4 + 2 * i + 1][n]) << 16);
            short* dst = xT + ((size_t)b * NTOK + n0 + n) * CIN + c0 + c4;
            ((uint4*)dst)[0] = make_uint4(buf[0], buf[1], buf[2], buf[3]);
            ((uint4*)dst)[1] = make_uint4(buf[4], buf[5], buf[6], buf[7]);
            __syncthreads();
        }
    }
    gbar(bar);

    // ================= P1: QKV GEMM, BM=192/BN=128, exactly 288 units ======
    {
        const int K = CIN;
        int u = bid;
        int nx = u % 18, oy = (u / 18) % 8, b = u / 144;
        int o0 = oy * 192, n0 = nx * 128;
        const short* pa = wqb + (size_t)(o0 + l31) * K + h * 8;
        const short* pb = xT + ((size_t)b * NTOK + n0 + wv * 32 + l31) * K + h * 8;

        f32x16 acc[6];
#pragma unroll
        for (int rb = 0; rb < 6; rb++)
#pragma unroll
            for (int r = 0; r < 16; r++) acc[rb][r] = 0.f;

#pragma unroll 2
        for (int kt = 0; kt < K; kt += 16) {
            bfrag bb = *(const bfrag*)(pb + kt);
#pragma unroll
            for (int rb = 0; rb < 6; rb++) {
                bfrag a = *(const bfrag*)(pa + (size_t)(rb * 32) * K + kt);
                acc[rb] = __builtin_amdgcn_mfma_f32_32x32x16_bf16(a, bb, acc[rb], 0, 0, 0);
            }
        }

        int nn = n0 + wv * 32 + l31;
#pragma unroll
        for (int rb = 0; rb < 6; rb++) {
            int ob = o0 + rb * 32;
            if (ob < 1024) {
                float* Q = qkf + (size_t)b * 1024 * NTOK;
#pragma unroll
                for (int r = 0; r < 16; r++) {
                    int ml = (r & 3) + 8 * (r >> 2) + 4 * h;
                    Q[(size_t)(ob + ml) * NTOK + nn] = acc[rb][r];
                }
            } else {
                short* V = vbp + (size_t)b * 512 * NTOK;
                int ov = ob - 1024;
#pragma unroll
                for (int r = 0; r < 16; r++) {
                    int ml = (r & 3) + 8 * (r >> 2) + 4 * h;
                    V[(size_t)(ov + ml) * NTOK + nn] = (short)f2bf(acc[rb][r]);
                }
            }
        }
    }
    gbar(bar);

    // ================= P2: row inverse L2 norms, 2048 rows =================
    for (int row = bid; row < 2048; row += NBLK) {
        int b = row >> 10, o = row & 1023;
        const float* p = qkf + ((size_t)b * 1024 + o) * NTOK;
        float s = 0.f;
        for (int i = tid; i < NTOK / 4; i += 256) {
            float4 v = ((const float4*)p)[i];
            s += v.x * v.x + v.y * v.y + v.z * v.z + v.w * v.w;
        }
#pragma unroll
        for (int off = 32; off > 0; off >>= 1) s += __shfl_down(s, off, 64);
        if ((tid & 63) == 0) wsred[tid >> 6] = s;
        __syncthreads();
        if (tid == 0) {
            float tot = wsred[0] + wsred[1] + wsred[2] + wsred[3];
            invn[row] = 1.f / fmaxf(sqrtf(tot), 1e-12f);
        }
        __syncthreads();
    }
    gbar(bar);

    // ================= P3: pack normalized q (x log2e), k -> qkt, 1152 =====
    for (int u = bid; u < 1152; u += NBLK) {
        int n0 = (u % 36) * 64, bh = (u / 36) % 16, sel = u / 576;
        int b = bh >> 3, hh = bh & 7;
        const float* src = qkf + ((size_t)b * 1024 + sel * 512 + hh * 64) * NTOK;
        int base = b * 1024 + sel * 512 + hh * 64;
        float extra = sel == 0 ? LOG2E : 1.f;

        for (int d = wv; d < 64; d += 4)
            sT[d][lane] = src[(size_t)d * NTOK + n0 + lane] * (invn[base + d] * extra);
        __syncthreads();

        int n = tid >> 2, c4 = (tid & 3) * 16;
        unsigned buf[8];
#pragma unroll
        for (int i = 0; i < 8; i++)
            buf[i] = f2bf(sT[c4 + 2 * i][n]) | (f2bf(sT[c4 + 2 * i + 1][n]) << 16);
        short* dst = qkt + (size_t)sel * ((size_t)16 * NTOK * 64)
                         + ((size_t)bh * NTOK + n0 + n) * 64 + c4;
        ((uint4*)dst)[0] = make_uint4(buf[0], buf[1], buf[2], buf[3]);
        ((uint4*)dst)[1] = make_uint4(buf[4], buf[5], buf[6], buf[7]);
        __syncthreads();
    }
    gbar(bar);

    // ================= P4: attention (R7 structure verbatim, 288 units) ====
    {
        int g = bid & 31;
        int bh = g >> 1, ms = g & 1;
        int ntile = bid >> 5;
        int b = bh >> 3, hh = bh & 7;
        int nb0 = ntile * 256 + wv * 32;
        int nb1 = nb0 + 128;
        int mbase = ms * (NTOK / 2);

        const short* Qt = qkt + (size_t)bh * NTOK * 64;
        const short* kp = qkt + (size_t)16 * NTOK * 64
                        + ((size_t)bh * NTOK + mbase + l31) * 64 + h * 8;
        const short* vl = vbp + ((size_t)b * 512 + hh * 64 + l31) * NTOK + mbase + h * 8;
        const short* vh2 = vl + (size_t)32 * NTOK;

        bfrag bQ0[4], bQ1[4];
        {
            const short* q0 = Qt + (size_t)(nb0 + l31) * 64 + h * 8;
            const short* q1 = Qt + (size_t)(nb1 + l31) * 64 + h * 8;
#pragma unroll
            for (int i = 0; i < 4; i++) {
                bQ0[i] = *(const bfrag*)(q0 + i * 16);
                bQ1[i] = *(const bfrag*)(q1 + i * 16);
            }
        }

        f32x16 aL0, aH0, aL1, aH1;
#pragma unroll
        for (int r = 0; r < 16; r++) { aL0[r] = 0.f; aH0[r] = 0.f; aL1[r] = 0.f; aH1[r] = 0.f; }
        float s00 = 0.f, s01 = 0.f, s10 = 0.f, s11 = 0.f;

#pragma unroll 2
        for (int it = 0; it < 36; it++) {
            bfrag k0 = *(const bfrag*)(kp);
            bfrag k1 = *(const bfrag*)(kp + 16);
            bfrag k2 = *(const bfrag*)(kp + 32);
            bfrag k3 = *(const bfrag*)(kp + 48);
            bfrag v00 = *(const bfrag*)(vl);
            bfrag v01 = *(const bfrag*)(vl + 16);
            bfrag v10 = *(const bfrag*)(vh2);
            bfrag v11 = *(const bfrag*)(vh2 + 16);
            kp += 2048; vl += 32; vh2 += 32;

            bfrag P00, P01, P10, P11;
            {
                f32x16 accS;
#pragma unroll
                for (int r = 0; r < 16; r++) accS[r] = 0.f;
                accS = __builtin_amdgcn_mfma_f32_32x32x16_bf16(k0, bQ0[0], accS, 0, 0, 0);
                accS = __builtin_amdgcn_mfma_f32_32x32x16_bf16(k1, bQ0[1], accS, 0, 0, 0);
                accS = __builtin_amdgcn_mfma_f32_32x32x16_bf16(k2, bQ0[2], accS, 0, 0, 0);
                accS = __builtin_amdgcn_mfma_f32_32x32x16_bf16(k3, bQ0[3], accS, 0, 0, 0);
                softmax_frag(accS, h, s00, s01, P00, P01);
            }
            {
                f32x16 accS;
#pragma unroll
                for (int r = 0; r < 16; r++) accS[r] = 0.f;
                accS = __builtin_amdgcn_mfma_f32_32x32x16_bf16(k0, bQ1[0], accS, 0, 0, 0);
                accS = __builtin_amdgcn_mfma_f32_32x32x16_bf16(k1, bQ1[1], accS, 0, 0, 0);
                accS = __builtin_amdgcn_mfma_f32_32x32x16_bf16(k2, bQ1[2], accS, 0, 0, 0);
                accS = __builtin_amdgcn_mfma_f32_32x32x16_bf16(k3, bQ1[3], accS, 0, 0, 0);
                softmax_frag(accS, h, s10, s11, P10, P11);
            }
            aL0 = __builtin_amdgcn_mfma_f32_32x32x16_bf16(P00, v00, aL0, 0, 0, 0);
            aL0 = __builtin_amdgcn_mfma_f32_32x32x16_bf16(P01, v01, aL0, 0, 0, 0);
            aH0 = __builtin_amdgcn_mfma_f32_32x32x16_bf16(P00, v10, aH0, 0, 0, 0);
            aH0 = __builtin_amdgcn_mfma_f32_32x32x16_bf16(P01, v11, aH0, 0, 0, 0);
            aL1 = __builtin_amdgcn_mfma_f32_32x32x16_bf16(P10, v00, aL1, 0, 0, 0);
            aL1 = __builtin_amdgcn_mfma_f32_32x32x16_bf16(P11, v01, aL1, 0, 0, 0);
            aH1 = __builtin_amdgcn_mfma_f32_32x32x16_bf16(P10, v10, aH1, 0, 0, 0);
            aH1 = __builtin_amdgcn_mfma_f32_32x32x16_bf16(P11, v11, aH1, 0, 0, 0);
        }

        float p0 = s00 + s01;
        p0 += __shfl_xor(p0, 32, 64);
        float p1 = s10 + s11;
        p1 += __shfl_xor(p1, 32, 64);
        if (h == 0) {
            lsum[((size_t)ms * 16 + bh) * NTOK + nb0 + l31] = p0;
            lsum[((size_t)ms * 16 + bh) * NTOK + nb1 + l31] = p1;
        }

        float* Ob = Opart + (size_t)ms * (2ull * NTOK * HID)
                  + (size_t)b * NTOK * HID + hh * 64;
#pragma unroll
        for (int r = 0; r < 16; r++) {
            int ml = (r & 3) + 8 * (r >> 2) + 4 * h;
            Ob[(size_t)(nb0 + ml) * HID + l31] = aL0[r];
            Ob[(size_t)(nb0 + ml) * HID + 32 + l31] = aH0[r];
            Ob[(size_t)(nb1 + ml) * HID + l31] = aL1[r];
            Ob[(size_t)(nb1 + ml) * HID + 32 + l31] = aH1[r];
        }
    }
    gbar(bar);

    // ================= P5: combine splits -> aoT bf16 (4 exact sweeps) =====
    for (size_t item = (size_t)bid * 256 + tid; item < 294912; item += (size_t)NBLK * 256) {
        size_t e = item * 8;
        int c = (int)(e & 511);
        size_t row = e >> 9;
        int b = (int)(row / NTOK), n = (int)(row - (size_t)b * NTOK);
        int hh = c >> 6;
        float l0 = lsum[(size_t)(b * 8 + hh) * NTOK + n];
        float l1 = lsum[(size_t)(16 + b * 8 + hh) * NTOK + n];
        float inv = 1.f / (l0 + l1);
        const float* P0 = Opart + e;
        const float* P1 = Opart + (size_t)2 * NTOK * HID + e;
        float4 a0 = ((const float4*)P0)[0], a1 = ((const float4*)P0)[1];
        float4 c0 = ((const float4*)P1)[0], c1 = ((const float4*)P1)[1];
        unsigned b0 = f2bf((a0.x + c0.x) * inv) | (f2bf((a0.y + c0.y) * inv) << 16);
        unsigned b1 = f2bf((a0.z + c0.z) * inv) | (f2bf((a0.w + c0.w) * inv) << 16);
        unsigned b2 = f2bf((a1.x + c1.x) * inv) | (f2bf((a1.y + c1.y) * inv) << 16);
        unsigned b3 = f2bf((a1.z + c1.z) * inv) | (f2bf((a1.w + c1.w) * inv) << 16);
        *((uint4*)(aoT + e)) = make_uint4(b0, b1, b2, b3);
    }
    gbar(bar);

    // ================= P6: proj GEMM + bias, BM=64/BN=64, 288 units ========
    {
        const int K = HID;
        int u = bid;
        int n0 = (u % 36) * 64, o0 = ((u / 36) % 4) * 64, b = u / 144;
        int ow = o0 + (wv & 1) * 32;
        int nn = n0 + (wv >> 1) * 32 + l31;

        const short* pa = wpb + (size_t)(ow + l31) * K + h * 8;
        const short* pb = aoT + ((size_t)b * NTOK + nn) * K + h * 8;

        f32x16 acc;
#pragma unroll
        for (int r = 0; r < 16; r++) acc[r] = 0.f;

#pragma unroll 4
        for (int kt = 0; kt < K; kt += 16) {
            bfrag a = *(const bfrag*)(pa + kt);
            bfrag bb = *(const bfrag*)(pb + kt);
            acc = __builtin_amdgcn_mfma_f32_32x32x16_bf16(a, bb, acc, 0, 0, 0);
        }

#pragma unroll
        for (int r = 0; r < 16; r++) {
            int o = ow + (r & 3) + 8 * (r >> 2) + 4 * h;
            y[((size_t)b * CIN + o) * NTOK + nn] = acc[r] + bias[o];
        }
    }
}

// ---------------------------------------------------------------------------
extern "C" void kernel_launch(void* const* d_in, const int* in_sizes, int n_in,
                              void* d_out, int out_size, void* d_ws, size_t ws_size,
                              hipStream_t stream)
{
    const float* x      = (const float*)d_in[0];
    const float* w_qkv  = (const float*)d_in[1];
    const float* w_proj = (const float*)d_in[2];
    const float* b_proj = (const float*)d_in[3];
    float* y = (float*)d_out;
    char* wsb = (char*)d_ws;

    // zero the software-barrier state (d_ws is poisoned 0xAA before each call)
    hipMemsetAsync(wsb + 36446208, 0, 16, stream);

    mega<<<NBLK, 256, 0, stream>>>(x, w_qkv, w_proj, b_proj, y, wsb);
}

// Round 11
// 207.484 us; speedup vs baseline: 2.6675x; 2.6675x over previous
//
#include <hip/hip_runtime.h>
#include <math.h>

#define NTOK 2304      // 48*48 tokens
#define BATCH 2
#define CIN 256
#define HID 512        // 8 heads * 64
#define NH 8
#define LOG2E 1.44269504088896340736f
#define KP 68          // K row pitch in shorts (136 B) -> 2-way LDS max (free)
#define VP 36          // V row pitch in shorts (72 B)  -> 2-way LDS max (free)

typedef __attribute__((ext_vector_type(8))) short bfrag;    // 8 bf16 (4 VGPRs)
typedef __attribute__((ext_vector_type(16))) float f32x16;  // MFMA 32x32 accumulator

#if __has_builtin(__builtin_amdgcn_exp2f)
#define EXP2(x) __builtin_amdgcn_exp2f(x)
#else
#define EXP2(x) exp2f(x)
#endif

// fp32 -> bf16 (RNE)
__device__ __forceinline__ unsigned f2bf(float f) {
    unsigned u = __float_as_uint(f);
    u += 0x7FFF + ((u >> 16) & 1);
    return u >> 16;
}

// pack trunc(hi(b)) , trunc(hi(a)) -> one dword {bf16(b):bf16(a)} in 1 v_perm
__device__ __forceinline__ unsigned pk_trunc(float a, float b) {
    return __builtin_amdgcn_perm(__float_as_uint(b), __float_as_uint(a), 0x07060302u);
}

// exp2 + bf16-pack + lane^32 half-swap: accS (S^T quadrant, C-layout) ->
// two A-operand P frags; accumulates this lane's partial row sums.
__device__ __forceinline__ void softmax_frag(
    const f32x16& accS, int h, float& ps0, float& ps1, bfrag& P0, bfrag& P1)
{
    unsigned dw[8];
#pragma unroll
    for (int i = 0; i < 8; i++) {
        float plo = EXP2(accS[2 * i]);
        float phi = EXP2(accS[2 * i + 1]);
        dw[i] = pk_trunc(plo, phi);
        ps0 += __uint_as_float(dw[i] << 16);
        ps1 += __uint_as_float(dw[i] & 0xffff0000u);
    }
    unsigned sa0 = h ? dw[0] : dw[2], sb0 = h ? dw[1] : dw[3];
    unsigned sa1 = h ? dw[4] : dw[6], sb1 = h ? dw[5] : dw[7];
    unsigned ra0 = (unsigned)__shfl_xor((int)sa0, 32, 64);
    unsigned rb0 = (unsigned)__shfl_xor((int)sb0, 32, 64);
    unsigned ra1 = (unsigned)__shfl_xor((int)sa1, 32, 64);
    unsigned rb1 = (unsigned)__shfl_xor((int)sb1, 32, 64);
    union { bfrag f; unsigned u[4]; } U0, U1;
    U0.u[0] = h ? ra0 : dw[0];  U0.u[1] = h ? rb0 : dw[1];
    U0.u[2] = h ? dw[2] : ra0;  U0.u[3] = h ? dw[3] : rb0;
    U1.u[0] = h ? ra1 : dw[4];  U1.u[1] = h ? rb1 : dw[5];
    U1.u[2] = h ? dw[6] : ra1;  U1.u[3] = h ? dw[7] : rb1;
    P0 = U0.f; P1 = U1.f;
}

// ---------------------------------------------------------------------------
// Fused input pack: blocks [0,256) pack both weight matrices elementwise;
// blocks [256,544) transpose-pack x fp32 [b][256][2304] -> bf16 xT [b][n][256].
// ---------------------------------------------------------------------------
__global__ __launch_bounds__(256) void pack_inputs(
    const float* __restrict__ wq, short* __restrict__ wqb,
    const float* __restrict__ wp, short* __restrict__ wpb,
    const float* __restrict__ x, short* __restrict__ xT)
{
    int bid = blockIdx.x;
    int tid = threadIdx.x;
    if (bid < 256) {
        int e = (bid * 256 + tid) * 8;
        const int NQ = 1536 * 256;
        const float* src; short* dst;
        if (e < NQ) { src = wq + e; dst = wqb + e; }
        else        { src = wp + (e - NQ); dst = wpb + (e - NQ); }
        float4 v0 = ((const float4*)src)[0];
        float4 v1 = ((const float4*)src)[1];
        unsigned b0 = f2bf(v0.x) | (f2bf(v0.y) << 16);
        unsigned b1 = f2bf(v0.z) | (f2bf(v0.w) << 16);
        unsigned b2 = f2bf(v1.x) | (f2bf(v1.y) << 16);
        unsigned b3 = f2bf(v1.z) | (f2bf(v1.w) << 16);
        *((uint4*)dst) = make_uint4(b0, b1, b2, b3);
        return;
    }
    int idx = bid - 256;                 // 288 transpose tiles
    int n0 = (idx % 36) * 64;
    int c0 = ((idx / 36) & 3) * 64;
    int b = idx / 144;
    __shared__ float sT[64][65];
    int lane = tid & 63, wv = tid >> 6;
    for (int c = wv; c < 64; c += 4)
        sT[c][lane] = x[((size_t)b * CIN + c0 + c) * NTOK + n0 + lane];
    __syncthreads();
    int n = tid >> 2, c4 = (tid & 3) * 16;
    unsigned buf[8];
#pragma unroll
    for (int i = 0; i < 8; i++)
        buf[i] = f2bf(sT[c4 + 2 * i][n]) | (f2bf(sT[c4 + 2 * i + 1][n]) << 16);
    short* dst = xT + ((size_t)b * NTOK + n0 + n) * CIN + c0 + c4;
    ((uint4*)dst)[0] = make_uint4(buf[0], buf[1], buf[2], buf[3]);
    ((uint4*)dst)[1] = make_uint4(buf[4], buf[5], buf[6], buf[7]);
}

// ---------------------------------------------------------------------------
// QKV GEMM (MFMA): BM=128, BN=128, K=256. rows o<1024 (q,k) -> fp32 qkf;
// rows >=1024 (v) -> bf16 vb [b][512][NTOK]. grid (18, 12, 2).
// ---------------------------------------------------------------------------
__global__ __launch_bounds__(256, 2) void gemm_qkv(
    const short* __restrict__ A, const short* __restrict__ B,
    float* __restrict__ qkf, short* __restrict__ vb)
{
    const int K = CIN;
    int b = blockIdx.z;
    int o0 = blockIdx.y * 128;
    int n0 = blockIdx.x * 128;
    int tid = threadIdx.x, wv = tid >> 6, lane = tid & 63;
    int h = lane >> 5, l31 = lane & 31;

    const short* pa = A + (size_t)(o0 + l31) * K + h * 8;
    const short* pb = B + ((size_t)b * NTOK + n0 + wv * 32 + l31) * K + h * 8;

    f32x16 acc[4];
#pragma unroll
    for (int rb = 0; rb < 4; rb++)
#pragma unroll
        for (int r = 0; r < 16; r++) acc[rb][r] = 0.f;

#pragma unroll 2
    for (int kt = 0; kt < K; kt += 16) {
        bfrag a0 = *(const bfrag*)(pa + kt);
        bfrag a1 = *(const bfrag*)(pa + (size_t)32 * K + kt);
        bfrag a2 = *(const bfrag*)(pa + (size_t)64 * K + kt);
        bfrag a3 = *(const bfrag*)(pa + (size_t)96 * K + kt);
        bfrag bb = *(const bfrag*)(pb + kt);
        acc[0] = __builtin_amdgcn_mfma_f32_32x32x16_bf16(a0, bb, acc[0], 0, 0, 0);
        acc[1] = __builtin_amdgcn_mfma_f32_32x32x16_bf16(a1, bb, acc[1], 0, 0, 0);
        acc[2] = __builtin_amdgcn_mfma_f32_32x32x16_bf16(a2, bb, acc[2], 0, 0, 0);
        acc[3] = __builtin_amdgcn_mfma_f32_32x32x16_bf16(a3, bb, acc[3], 0, 0, 0);
    }

    int nn = n0 + wv * 32 + l31;
    if (o0 < 1024) {
        float* Q = qkf + (size_t)b * 1024 * NTOK;
#pragma unroll
        for (int rb = 0; rb < 4; rb++)
#pragma unroll
            for (int r = 0; r < 16; r++) {
                int ml = (r & 3) + 8 * (r >> 2) + 4 * h;
                Q[(size_t)(o0 + rb * 32 + ml) * NTOK + nn] = acc[rb][r];
            }
    } else {
        short* V = vb + (size_t)b * 512 * NTOK;
        int ov = o0 - 1024;
#pragma unroll
        for (int rb = 0; rb < 4; rb++)
#pragma unroll
            for (int r = 0; r < 16; r++) {
                int ml = (r & 3) + 8 * (r >> 2) + 4 * h;
                V[(size_t)(ov + rb * 32 + ml) * NTOK + nn] = (short)f2bf(acc[rb][r]);
            }
    }
}

// ---------------------------------------------------------------------------
// Row inverse L2-norm over tokens (float4 reads). rows 0..2047.
// ---------------------------------------------------------------------------
__global__ __launch_bounds__(256) void rownorm(
    const float* __restrict__ qkf, float* __restrict__ invn)
{
    int row = blockIdx.x;
    int b = row >> 10, o = row & 1023;
    const float* p = qkf + ((size_t)b * 1024 + o) * NTOK;
    int tid = threadIdx.x;
    float s = 0.f;
    for (int i = tid; i < NTOK / 4; i += 256) {
        float4 v = ((const float4*)p)[i];
        s += v.x * v.x + v.y * v.y + v.z * v.z + v.w * v.w;
    }
#pragma unroll
    for (int off = 32; off > 0; off >>= 1) s += __shfl_down(s, off, 64);
    __shared__ float ws[4];
    if ((tid & 63) == 0) ws[tid >> 6] = s;
    __syncthreads();
    if (tid == 0) {
        float tot = ws[0] + ws[1] + ws[2] + ws[3];
        invn[row] = 1.f / fmaxf(sqrtf(tot), 1e-12f);
    }
}

// ---------------------------------------------------------------------------
// Pack normalized q,k -> bf16 token-major qkt [sel][bh][n][64].
// q additionally scaled by log2(e) so attention uses exp2 directly.
// ---------------------------------------------------------------------------
__global__ __launch_bounds__(256) void pack_qk(
    const float* __restrict__ qkf, const float* __restrict__ invn,
    short* __restrict__ qkt)
{
    int n0 = blockIdx.x * 64;
    int bh = blockIdx.y;
    int sel = blockIdx.z;
    int b = bh >> 3, h = bh & 7;
    const float* src = qkf + ((size_t)b * 1024 + sel * 512 + h * 64) * NTOK;
    int base = b * 1024 + sel * 512 + h * 64;
    float extra = sel == 0 ? LOG2E : 1.f;

    __shared__ float sT[64][65];
    int tid = threadIdx.x, lane = tid & 63, wv = tid >> 6;
    for (int d = wv; d < 64; d += 4)
        sT[d][lane] = src[(size_t)d * NTOK + n0 + lane] * (invn[base + d] * extra);
    __syncthreads();

    int n = tid >> 2, c4 = (tid & 3) * 16;
    unsigned buf[8];
#pragma unroll
    for (int i = 0; i < 8; i++)
        buf[i] = f2bf(sT[c4 + 2 * i][n]) | (f2bf(sT[c4 + 2 * i + 1][n]) << 16);
    short* dst = qkt + (size_t)sel * ((size_t)16 * NTOK * 64)
                     + ((size_t)bh * NTOK + n0 + n) * 64 + c4;
    ((uint4*)dst)[0] = make_uint4(buf[0], buf[1], buf[2], buf[3]);
    ((uint4*)dst)[1] = make_uint4(buf[4], buf[5], buf[6], buf[7]);
}

// ---------------------------------------------------------------------------
// Barrier-light attention: LDS double-buffered K/V staging.
// 1-D grid 288 (R7 fat blocks + XCD swizzle): g=bid&31 -> (bh,ms),
// ntile=bid>>5; wave owns n-groups nb0 and nb0+128 sharing K/V.
// Per iter: each thread loads 16B K + 16B V for tile i+1 into registers,
// waves compute from LDS buf[i&1] (8x ds_read_b128, padded pitches ->
// <=2-way conflicts), staged regs written to buf[(i+1)&1], one barrier.
// Loads stay in flight across the whole compute body; staging VGPR cost = 8.
// ---------------------------------------------------------------------------
__global__ __launch_bounds__(256, 2) void attn_nb(
    const short* __restrict__ qkt,   // [2][16][2304][64] bf16 (q pre-scaled log2e)
    const short* __restrict__ vb,    // [2][512][2304] bf16
    float* __restrict__ Opart,       // [2 split][2][2304][512] fp32
    float* __restrict__ lsum)        // [2 split][16][2304] fp32
{
    __shared__ short sK[2][32 * KP];   // 2 x 4352 B
    __shared__ short sV[2][64 * VP];   // 2 x 4608 B (rows 0-31 Vlo, 32-63 Vhi)

    int bid = blockIdx.x;
    int g = bid & 31;
    int bh = g >> 1, ms = g & 1;
    int ntile = bid >> 5;
    int b = bh >> 3, hh = bh & 7;
    int tid = threadIdx.x, wv = tid >> 6, lane = tid & 63;
    int h = lane >> 5, l31 = lane & 31;
    int nb0 = ntile * 256 + wv * 32;
    int nb1 = nb0 + 128;
    int mbase = ms * (NTOK / 2);

    const short* Qt = qkt + (size_t)bh * NTOK * 64;
    const short* Kg = qkt + (size_t)16 * NTOK * 64 + (size_t)bh * NTOK * 64;
    const short* Vg = vb + ((size_t)b * 512 + hh * 64) * NTOK;

    // staging map: K = 32 rows x 8 chunks of 16B; V = 64 rows x 4 chunks
    int krow = tid >> 3, kch = tid & 7;
    int vr = (tid >> 7) * 32 + ((tid & 127) >> 2), vch = tid & 3;

    bfrag bQ0[4], bQ1[4];
    {
        const short* q0 = Qt + (size_t)(nb0 + l31) * 64 + h * 8;
        const short* q1 = Qt + (size_t)(nb1 + l31) * 64 + h * 8;
#pragma unroll
        for (int i = 0; i < 4; i++) {
            bQ0[i] = *(const bfrag*)(q0 + i * 16);
            bQ1[i] = *(const bfrag*)(q1 + i * 16);
        }
    }

    // stage tile 0
    {
        *(uint4*)(&sK[0][krow * KP + kch * 8]) =
            *(const uint4*)(Kg + (size_t)(mbase + krow) * 64 + kch * 8);
        *(uint4*)(&sV[0][vr * VP + vch * 8]) =
            *(const uint4*)(Vg + (size_t)vr * NTOK + mbase + vch * 8);
    }
    __syncthreads();

    f32x16 aL0, aH0, aL1, aH1;
#pragma unroll
    for (int r = 0; r < 16; r++) { aL0[r] = 0.f; aH0[r] = 0.f; aL1[r] = 0.f; aH1[r] = 0.f; }
    float s00 = 0.f, s01 = 0.f, s10 = 0.f, s11 = 0.f;

    for (int it = 0; it < 36; it++) {
        int cur = it & 1, nxt = cur ^ 1;
        // prefetch next tile into registers (in flight across compute)
        uint4 kpf, vpf;
        if (it < 35) {
            int m0 = mbase + (it + 1) * 32;
            kpf = *(const uint4*)(Kg + (size_t)(m0 + krow) * 64 + kch * 8);
            vpf = *(const uint4*)(Vg + (size_t)vr * NTOK + m0 + vch * 8);
        }

        // operand frags from current LDS buffer
        const short* kb = &sK[cur][l31 * KP + h * 8];
        bfrag k0 = *(const bfrag*)(kb);
        bfrag k1 = *(const bfrag*)(kb + 16);
        bfrag k2 = *(const bfrag*)(kb + 32);
        bfrag k3 = *(const bfrag*)(kb + 48);
        const short* vl = &sV[cur][l31 * VP + h * 8];
        const short* vh2 = &sV[cur][(32 + l31) * VP + h * 8];
        bfrag v00 = *(const bfrag*)(vl);
        bfrag v01 = *(const bfrag*)(vl + 16);
        bfrag v10 = *(const bfrag*)(vh2);
        bfrag v11 = *(const bfrag*)(vh2 + 16);

        bfrag P00, P01, P10, P11;
        {
            f32x16 accS;
#pragma unroll
            for (int r = 0; r < 16; r++) accS[r] = 0.f;
            accS = __builtin_amdgcn_mfma_f32_32x32x16_bf16(k0, bQ0[0], accS, 0, 0, 0);
            accS = __builtin_amdgcn_mfma_f32_32x32x16_bf16(k1, bQ0[1], accS, 0, 0, 0);
            accS = __builtin_amdgcn_mfma_f32_32x32x16_bf16(k2, bQ0[2], accS, 0, 0, 0);
            accS = __builtin_amdgcn_mfma_f32_32x32x16_bf16(k3, bQ0[3], accS, 0, 0, 0);
            softmax_frag(accS, h, s00, s01, P00, P01);
        }
        {
            f32x16 accS;
#pragma unroll
            for (int r = 0; r < 16; r++) accS[r] = 0.f;
            accS = __builtin_amdgcn_mfma_f32_32x32x16_bf16(k0, bQ1[0], accS, 0, 0, 0);
            accS = __builtin_amdgcn_mfma_f32_32x32x16_bf16(k1, bQ1[1], accS, 0, 0, 0);
            accS = __builtin_amdgcn_mfma_f32_32x32x16_bf16(k2, bQ1[2], accS, 0, 0, 0);
            accS = __builtin_amdgcn_mfma_f32_32x32x16_bf16(k3, bQ1[3], accS, 0, 0, 0);
            softmax_frag(accS, h, s10, s11, P10, P11);
        }
        aL0 = __builtin_amdgcn_mfma_f32_32x32x16_bf16(P00, v00, aL0, 0, 0, 0);
        aL0 = __builtin_amdgcn_mfma_f32_32x32x16_bf16(P01, v01, aL0, 0, 0, 0);
        aH0 = __builtin_amdgcn_mfma_f32_32x32x16_bf16(P00, v10, aH0, 0, 0, 0);
        aH0 = __builtin_amdgcn_mfma_f32_32x32x16_bf16(P01, v11, aH0, 0, 0, 0);
        aL1 = __builtin_amdgcn_mfma_f32_32x32x16_bf16(P10, v00, aL1, 0, 0, 0);
        aL1 = __builtin_amdgcn_mfma_f32_32x32x16_bf16(P11, v01, aL1, 0, 0, 0);
        aH1 = __builtin_amdgcn_mfma_f32_32x32x16_bf16(P10, v10, aH1, 0, 0, 0);
        aH1 = __builtin_amdgcn_mfma_f32_32x32x16_bf16(P11, v11, aH1, 0, 0, 0);

        // write staged tile into next buffer, flip
        if (it < 35) {
            *(uint4*)(&sK[nxt][krow * KP + kch * 8]) = kpf;
            *(uint4*)(&sV[nxt][vr * VP + vch * 8]) = vpf;
        }
        __syncthreads();
    }

    float p0 = s00 + s01;
    p0 += __shfl_xor(p0, 32, 64);
    float p1 = s10 + s11;
    p1 += __shfl_xor(p1, 32, 64);
    if (h == 0) {
        lsum[((size_t)ms * 16 + bh) * NTOK + nb0 + l31] = p0;
        lsum[((size_t)ms * 16 + bh) * NTOK + nb1 + l31] = p1;
    }

    float* Ob = Opart + (size_t)ms * (2ull * NTOK * HID)
              + (size_t)b * NTOK * HID + hh * 64;
#pragma unroll
    for (int r = 0; r < 16; r++) {
        int ml = (r & 3) + 8 * (r >> 2) + 4 * h;
        Ob[(size_t)(nb0 + ml) * HID + l31] = aL0[r];
        Ob[(size_t)(nb0 + ml) * HID + 32 + l31] = aH0[r];
        Ob[(size_t)(nb1 + ml) * HID + l31] = aL1[r];
        Ob[(size_t)(nb1 + ml) * HID + 32 + l31] = aH1[r];
    }
}

// ---------------------------------------------------------------------------
// Combine two m-splits, normalize, pack bf16 aoT [b][n][512]. 8 elems/thread.
// ---------------------------------------------------------------------------
__global__ __launch_bounds__(256) void combine(
    const float* __restrict__ Opart, const float* __restrict__ lsum,
    short* __restrict__ aoT)
{
    size_t e = ((size_t)blockIdx.x * 256 + threadIdx.x) * 8;
    int c = (int)(e & 511);
    size_t row = e >> 9;                 // b*2304 + n
    int b = (int)(row / NTOK), n = (int)(row - (size_t)b * NTOK);
    int hh = c >> 6;
    float l0 = lsum[(size_t)(b * 8 + hh) * NTOK + n];
    float l1 = lsum[(size_t)16 * NTOK + (size_t)(b * 8 + hh) * NTOK + n];
    float inv = 1.f / (l0 + l1);
    const float* P0 = Opart + e;
    const float* P1 = Opart + (size_t)2 * NTOK * HID + e;
    float4 a0 = ((const float4*)P0)[0], a1 = ((const float4*)P0)[1];
    float4 c0 = ((const float4*)P1)[0], c1 = ((const float4*)P1)[1];
    unsigned b0 = f2bf((a0.x + c0.x) * inv) | (f2bf((a0.y + c0.y) * inv) << 16);
    unsigned b1 = f2bf((a0.z + c0.z) * inv) | (f2bf((a0.w + c0.w) * inv) << 16);
    unsigned b2 = f2bf((a1.x + c1.x) * inv) | (f2bf((a1.y + c1.y) * inv) << 16);
    unsigned b3 = f2bf((a1.z + c1.z) * inv) | (f2bf((a1.w + c1.w) * inv) << 16);
    *((uint4*)(aoT + e)) = make_uint4(b0, b1, b2, b3);
}

// ---------------------------------------------------------------------------
// Proj GEMM (MFMA, direct store + bias). BM=64, BN=128, K=512.
// grid (18, 4, 2). unroll 4.
// ---------------------------------------------------------------------------
__global__ __launch_bounds__(256, 2) void gemm_proj(
    const short* __restrict__ A, const short* __restrict__ B,
    const float* __restrict__ bias, float* __restrict__ y)
{
    const int K = HID;
    int b = blockIdx.z;
    int o0 = blockIdx.y * 64;
    int n0 = blockIdx.x * 128;
    int tid = threadIdx.x, wv = tid >> 6, lane = tid & 63;
    int h = lane >> 5, l31 = lane & 31;

    const short* pa0 = A + (size_t)(o0 + l31) * K + h * 8;
    const short* pa1 = pa0 + (size_t)32 * K;
    const short* pb  = B + ((size_t)b * NTOK + n0 + wv * 32 + l31) * K + h * 8;

    f32x16 acc0, acc1;
#pragma unroll
    for (int r = 0; r < 16; r++) { acc0[r] = 0.f; acc1[r] = 0.f; }

#pragma unroll 4
    for (int kt = 0; kt < K; kt += 16) {
        bfrag a0 = *(const bfrag*)(pa0 + kt);
        bfrag a1 = *(const bfrag*)(pa1 + kt);
        bfrag bb = *(const bfrag*)(pb + kt);
        acc0 = __builtin_amdgcn_mfma_f32_32x32x16_bf16(a0, bb, acc0, 0, 0, 0);
        acc1 = __builtin_amdgcn_mfma_f32_32x32x16_bf16(a1, bb, acc1, 0, 0, 0);
    }

    int nn = n0 + wv * 32 + l31;
#pragma unroll
    for (int r = 0; r < 16; r++) {
        int ml = (r & 3) + 8 * (r >> 2) + 4 * h;
        y[((size_t)b * CIN + o0 + ml) * NTOK + nn] = acc0[r] + bias[o0 + ml];
        y[((size_t)b * CIN + o0 + 32 + ml) * NTOK + nn] = acc1[r] + bias[o0 + 32 + ml];
    }
}

// ---------------------------------------------------------------------------
// Workspace (<= 36,446,208 B of 37,748,736):
//   [0, 18,874,368)           qkf fp32 [2][1024][2304]   (k2 -> k4)
//       then Opart fp32 [2 split][2][2304][512]          (k5 -> k6, exact fit)
//   [18,874,368, 23,592,960)  vb bf16 [2][512][2304]     (k2 -> k5)
//   [23,592,960, 33,030,144)  qkt bf16 [2][16][2304][64] (k4 -> k5)
//       then aoT bf16 [2][2304][512]                     (k6 -> k7)
//   [33,030,144, 33,325,056)  lsum fp32 [2][16][2304]    (k5 -> k6, over dead xT)
//   [33,030,144, 35,389,440)  xT bf16                     (k1 -> k2, dead at k5)
//   [35,389,440, 36,175,872)  wqb bf16
//   [36,175,872, 36,438,016)  wpb bf16
//   [36,438,016, 36,446,208)  invn fp32 [2048]
// ---------------------------------------------------------------------------
extern "C" void kernel_launch(void* const* d_in, const int* in_sizes, int n_in,
                              void* d_out, int out_size, void* d_ws, size_t ws_size,
                              hipStream_t stream)
{
    const float* x      = (const float*)d_in[0];
    const float* w_qkv  = (const float*)d_in[1];
    const float* w_proj = (const float*)d_in[2];
    const float* b_proj = (const float*)d_in[3];
    float* y = (float*)d_out;

    float* qkf   = (float*)d_ws;
    float* Opart = (float*)d_ws;
    short* vb    = (short*)((char*)d_ws + 18874368);
    short* qkt   = (short*)((char*)d_ws + 23592960);
    short* aoT   = (short*)((char*)d_ws + 23592960);
    float* lsum  = (float*)((char*)d_ws + 33030144);
    short* xT    = (short*)((char*)d_ws + 33030144);
    short* wqb   = (short*)((char*)d_ws + 35389440);
    short* wpb   = (short*)((char*)d_ws + 36175872);
    float* invn  = (float*)((char*)d_ws + 36438016);

    // k1: pack weights + transpose-pack x (one dispatch)
    pack_inputs<<<544, 256, 0, stream>>>(w_qkv, wqb, w_proj, wpb, x, xT);
    // k2: QKV GEMM, BM=128 (q,k fp32; v straight to bf16)
    gemm_qkv<<<dim3(NTOK / 128, 1536 / 128, BATCH), 256, 0, stream>>>(
        wqb, xT, qkf, vb);
    // k3: inverse row norms
    rownorm<<<2048, 256, 0, stream>>>(qkf, invn);
    // k4: pack normalized q (x log2e), k -> token-major bf16
    pack_qk<<<dim3(NTOK / 64, BATCH * NH, 2), 256, 0, stream>>>(qkf, invn, qkt);
    // k5: attention — 288 fat blocks, XCD swizzle, LDS double-buffered K/V
    attn_nb<<<288, 256, 0, stream>>>(qkt, vb, Opart, lsum);
    // k6: combine splits -> aoT bf16 (over dead qkt)
    combine<<<(BATCH * NTOK * HID / 8) / 256, 256, 0, stream>>>(Opart, lsum, aoT);
    // k7: proj GEMM, direct store + bias
    gemm_proj<<<dim3(NTOK / 128, CIN / 64, BATCH), 256, 0, stream>>>(
        wpb, aoT, b_proj, y);
}